// Round 1
// baseline (190.334 us; speedup 1.0000x reference)
//
#include <hip/hip_runtime.h>
#include <math.h>

#define DD 16
#define LL 1024
#define BB 1024
#define NCHUNK (LL/4)   // 256 chunks of 4 steps

// ---------------------------------------------------------------------------
// Kernel A: build chunk table.
// T[c*16+m] = K(4c, m>>3&1) @ K(4c+1, m>>2&1) @ K(4c+2, m>>1&1) @ K(4c+3, m&1)
// One block per (c,m), 256 threads, thread t = i*16+k computes element (i,k).
// ---------------------------------------------------------------------------
__global__ void build_table(const float* __restrict__ km, float* __restrict__ T) {
    const int c = blockIdx.x >> 4;
    const int m = blockIdx.x & 15;
    const int t = threadIdx.x;
    const int i = t >> 4, k = t & 15;
    __shared__ float M[4][256];
    __shared__ float buf[256];
    const int xs0 = (m >> 3) & 1, xs1 = (m >> 2) & 1, xs2 = (m >> 1) & 1, xs3 = m & 1;
    M[0][t] = km[((4*c + 0)*2 + xs0)*256 + t];
    M[1][t] = km[((4*c + 1)*2 + xs1)*256 + t];
    M[2][t] = km[((4*c + 2)*2 + xs2)*256 + t];
    M[3][t] = km[((4*c + 3)*2 + xs3)*256 + t];
    __syncthreads();
    float acc = 0.f;
    #pragma unroll
    for (int j = 0; j < 16; ++j) acc += M[0][i*16+j] * M[1][j*16+k];
    buf[t] = acc;
    __syncthreads();
    acc = 0.f;
    #pragma unroll
    for (int j = 0; j < 16; ++j) acc += buf[i*16+j] * M[2][j*16+k];
    __syncthreads();
    buf[t] = acc;
    __syncthreads();
    acc = 0.f;
    #pragma unroll
    for (int j = 0; j < 16; ++j) acc += buf[i*16+j] * M[3][j*16+k];
    T[(size_t)blockIdx.x*256 + t] = acc;
}

// ---------------------------------------------------------------------------
// Kernel B: per-(batch, segment) partial products.
// item = b*S + s; 16 threads per item; thread j owns carry row j in registers.
// CHUNK=4: steps through the precomputed table. CHUNK=1: raw kernel matrices.
// ---------------------------------------------------------------------------
template<int CHUNK>
__global__ void seg_prod(const float* __restrict__ T,
                         const int* __restrict__ x,
                         float* __restrict__ P,
                         const int S, const int lgS) {
    const int tid  = blockIdx.x * blockDim.x + threadIdx.x;
    const int j    = tid & 15;
    const int item = tid >> 4;
    if (item >= BB * S) return;
    const int s = item & (S - 1);
    const int b = item >> lgS;

    float c[16];
    #pragma unroll
    for (int q = 0; q < 16; ++q) c[q] = (q == j) ? 1.f : 0.f;

    const int nsteps = (CHUNK == 4 ? NCHUNK : LL) / S;
    const int base   = s * nsteps;

    for (int cc = 0; cc < nsteps; ++cc) {
        const float4* __restrict__ Mrow;
        if (CHUNK == 4) {
            const int cidx = base + cc;
            const int4 xv = *reinterpret_cast<const int4*>(x + (size_t)b*LL + 4*cidx);
            const int m = xv.x*8 + xv.y*4 + xv.z*2 + xv.w;
            Mrow = reinterpret_cast<const float4*>(T + ((size_t)cidx*16 + m)*256);
        } else {
            const int l = base + cc;
            const int xv = x[(size_t)b*LL + l];
            Mrow = reinterpret_cast<const float4*>(T + ((size_t)l*2 + xv)*256);
        }
        float4 n0 = make_float4(0.f,0.f,0.f,0.f), n1 = n0, n2 = n0, n3 = n0;
        #pragma unroll
        for (int i = 0; i < 16; ++i) {
            const float a = c[i];
            const float4 r0 = Mrow[i*4+0];
            const float4 r1 = Mrow[i*4+1];
            const float4 r2 = Mrow[i*4+2];
            const float4 r3 = Mrow[i*4+3];
            n0.x += a*r0.x; n0.y += a*r0.y; n0.z += a*r0.z; n0.w += a*r0.w;
            n1.x += a*r1.x; n1.y += a*r1.y; n1.z += a*r1.z; n1.w += a*r1.w;
            n2.x += a*r2.x; n2.y += a*r2.y; n2.z += a*r2.z; n2.w += a*r2.w;
            n3.x += a*r3.x; n3.y += a*r3.y; n3.z += a*r3.z; n3.w += a*r3.w;
        }
        c[0]=n0.x; c[1]=n0.y; c[2]=n0.z; c[3]=n0.w;
        c[4]=n1.x; c[5]=n1.y; c[6]=n1.z; c[7]=n1.w;
        c[8]=n2.x; c[9]=n2.y; c[10]=n2.z; c[11]=n2.w;
        c[12]=n3.x; c[13]=n3.y; c[14]=n3.z; c[15]=n3.w;
    }
    float4* Pp = reinterpret_cast<float4*>(P + (size_t)item*256 + j*16);
    Pp[0] = make_float4(c[0],c[1],c[2],c[3]);
    Pp[1] = make_float4(c[4],c[5],c[6],c[7]);
    Pp[2] = make_float4(c[8],c[9],c[10],c[11]);
    Pp[3] = make_float4(c[12],c[13],c[14],c[15]);
}

// ---------------------------------------------------------------------------
// Kernel C: combine S partials per batch, trace, log.
// 64 threads/block = 4 batches/block, 16 threads per batch (row-per-thread).
// ---------------------------------------------------------------------------
__global__ void combine(const float* __restrict__ P, float* __restrict__ out,
                        const int S) {
    const int g = threadIdx.x >> 4;
    const int j = threadIdx.x & 15;
    const int b = blockIdx.x * 4 + g;

    float c[16];
    {
        const float4* p0 = reinterpret_cast<const float4*>(P + (size_t)(b*S)*256 + j*16);
        const float4 v0 = p0[0], v1 = p0[1], v2 = p0[2], v3 = p0[3];
        c[0]=v0.x; c[1]=v0.y; c[2]=v0.z; c[3]=v0.w;
        c[4]=v1.x; c[5]=v1.y; c[6]=v1.z; c[7]=v1.w;
        c[8]=v2.x; c[9]=v2.y; c[10]=v2.z; c[11]=v2.w;
        c[12]=v3.x; c[13]=v3.y; c[14]=v3.z; c[15]=v3.w;
    }
    for (int s = 1; s < S; ++s) {
        const float4* Mrow = reinterpret_cast<const float4*>(P + (size_t)(b*S + s)*256);
        float4 n0 = make_float4(0.f,0.f,0.f,0.f), n1 = n0, n2 = n0, n3 = n0;
        #pragma unroll
        for (int i = 0; i < 16; ++i) {
            const float a = c[i];
            const float4 r0 = Mrow[i*4+0];
            const float4 r1 = Mrow[i*4+1];
            const float4 r2 = Mrow[i*4+2];
            const float4 r3 = Mrow[i*4+3];
            n0.x += a*r0.x; n0.y += a*r0.y; n0.z += a*r0.z; n0.w += a*r0.w;
            n1.x += a*r1.x; n1.y += a*r1.y; n1.z += a*r1.z; n1.w += a*r1.w;
            n2.x += a*r2.x; n2.y += a*r2.y; n2.z += a*r2.z; n2.w += a*r2.w;
            n3.x += a*r3.x; n3.y += a*r3.y; n3.z += a*r3.z; n3.w += a*r3.w;
        }
        c[0]=n0.x; c[1]=n0.y; c[2]=n0.z; c[3]=n0.w;
        c[4]=n1.x; c[5]=n1.y; c[6]=n1.z; c[7]=n1.w;
        c[8]=n2.x; c[9]=n2.y; c[10]=n2.z; c[11]=n2.w;
        c[12]=n3.x; c[13]=n3.y; c[14]=n3.z; c[15]=n3.w;
    }
    // diagonal element of row j is c[j]; sum across the 16 lanes of this group
    float diag = c[j];
    #pragma unroll
    for (int off = 8; off >= 1; off >>= 1)
        diag += __shfl_xor(diag, off, 16);
    if (j == 0) out[b] = logf(diag);
}

// ---------------------------------------------------------------------------
extern "C" void kernel_launch(void* const* d_in, const int* in_sizes, int n_in,
                              void* d_out, int out_size, void* d_ws, size_t ws_size,
                              hipStream_t stream) {
    const int*   x  = (const int*)d_in[0];    // (B, L) int32
    const float* km = (const float*)d_in[1];  // (L, PHYS, D, D) fp32
    float* out = (float*)d_out;               // (B,) fp32

    const size_t tbytes = (size_t)NCHUNK * 16 * 256 * sizeof(float);   // 4 MiB

    int S = 16;
    const size_t pbytes16 = (size_t)BB * S * 256 * sizeof(float);      // 16 MiB

    if (ws_size >= tbytes + pbytes16) {
        float* Tbl = (float*)d_ws;
        float* P   = (float*)((char*)d_ws + tbytes);
        build_table<<<NCHUNK*16, 256, 0, stream>>>(km, Tbl);
        const int items = BB * S;
        seg_prod<4><<<items*16/256, 256, 0, stream>>>(Tbl, x, P, S, 4);
        combine<<<BB/4, 64, 0, stream>>>(P, out, S);
    } else {
        // fallback: no table, raw per-step selection; shrink S to fit
        while (S > 1 && (size_t)BB * S * 256 * sizeof(float) > ws_size) S >>= 1;
        int lgS = 0; for (int t = S; t > 1; t >>= 1) ++lgS;
        float* P = (float*)d_ws;
        const int items = BB * S;
        const int blocks = (items*16 + 255) / 256;
        seg_prod<1><<<blocks, 256, 0, stream>>>(km, x, P, S, lgS);
        combine<<<BB/4, 64, 0, stream>>>(P, out, S);
    }
}